// Round 1
// baseline (350.249 us; speedup 1.0000x reference)
//
#include <hip/hip_runtime.h>
#include <hip/hip_bf16.h>
#include <math.h>

#define BB 4
#define LL 5
#define HSZ 32
#define WSZ 32
#define PP (HSZ*WSZ)   // 1024
#define CC 256
#define MM 8
#define DD 32
#define II 256
#define TT 2
#define SCALE 0.17677669529663687f  // 1/sqrt(32)

// ---------------------------------------------------------------------------
// Kernel 1: fused LayerNorm + per-type QKV projection.
// Grid: 3 (mat) x 20 (b*L) x 32 (row tiles of 32 pixels) = 1920 blocks, 128 thr.
// LDS: XsT (k-major normalized X tile) + Wst (16-k W tile). 8x8 micro-tile.
// ---------------------------------------------------------------------------
__global__ __launch_bounds__(128) void k_ln_qkv(
    const float* __restrict__ x, const float* __restrict__ prior,
    const float* __restrict__ lnw, const float* __restrict__ lnb,
    const float* __restrict__ Wq, const float* __restrict__ bq,
    const float* __restrict__ Wk, const float* __restrict__ bk,
    const float* __restrict__ Wv, const float* __restrict__ bv,
    float* __restrict__ outq, float* __restrict__ outk, float* __restrict__ outv)
{
    __shared__ float XsT[256 * 36];   // [channel][row(32) pad 36]
    __shared__ float Wst[16 * 260];   // [k(16)][col(256) pad 260]
    __shared__ float lw[256], lb[256];

    const int tid = threadIdx.x;
    const int mat = blockIdx.x / 640;
    const int rem = blockIdx.x - mat * 640;
    const int bl  = rem >> 5;          // b*L + l
    const int rt  = rem & 31;
    const int bbi = bl / LL;
    const int l   = bl - bbi * LL;
    const int p0  = rt * 32;
    const int t   = (int)prior[(size_t)bl * (PP * 3) + 2];

    lw[tid]       = lnw[tid];
    lw[tid + 128] = lnw[tid + 128];
    lb[tid]       = lnb[tid];
    lb[tid + 128] = lnb[tid + 128];

    // ---- stage x rows + LayerNorm ----
    const int r  = tid >> 2;       // 0..31  (pixel within tile)
    const int jj = tid & 3;        // 4 threads per row
    const float* xrow = x + ((size_t)bl * PP + p0 + r) * CC;

    float4 xv[16];
    float s1 = 0.f, s2 = 0.f;
    #pragma unroll
    for (int u = 0; u < 16; ++u) {
        xv[u] = *(const float4*)(xrow + (jj + 4 * u) * 4);
        s1 += xv[u].x + xv[u].y + xv[u].z + xv[u].w;
        s2 += xv[u].x * xv[u].x + xv[u].y * xv[u].y + xv[u].z * xv[u].z + xv[u].w * xv[u].w;
    }
    s1 += __shfl_xor(s1, 1); s1 += __shfl_xor(s1, 2);
    s2 += __shfl_xor(s2, 1); s2 += __shfl_xor(s2, 2);
    const float mu   = s1 * (1.0f / 256.0f);
    const float var  = s2 * (1.0f / 256.0f) - mu * mu;
    const float rstd = rsqrtf(var + 1e-5f);

    __syncthreads();   // lw/lb ready

    #pragma unroll
    for (int u = 0; u < 16; ++u) {
        const int c = (jj + 4 * u) * 4;
        XsT[(c + 0) * 36 + r] = (xv[u].x - mu) * rstd * lw[c + 0] + lb[c + 0];
        XsT[(c + 1) * 36 + r] = (xv[u].y - mu) * rstd * lw[c + 1] + lb[c + 1];
        XsT[(c + 2) * 36 + r] = (xv[u].z - mu) * rstd * lw[c + 2] + lb[c + 2];
        XsT[(c + 3) * 36 + r] = (xv[u].w - mu) * rstd * lw[c + 3] + lb[c + 3];
    }

    // ---- select matrix ----
    const float* W; const float* bias; float* dst;
    if (mat == 0)      { W = Wq + (size_t)t * CC * II; bias = bq + t * II; dst = outq; }
    else if (mat == 1) { W = Wk + (size_t)t * CC * II; bias = bk + t * II; dst = outk; }
    else               { W = Wv + (size_t)t * CC * II; bias = bv + t * II; dst = outv; }

    const int rg = tid >> 5;       // 0..3
    const int cg = tid & 31;       // 0..31
    const int r0 = rg * 8;
    const int c0 = cg * 4;

    float acc[8][8];
    #pragma unroll
    for (int a = 0; a < 8; ++a)
        #pragma unroll
        for (int b2 = 0; b2 < 8; ++b2) acc[a][b2] = 0.f;

    for (int kt = 0; kt < 256; kt += 16) {
        __syncthreads();   // XsT ready (first iter) / Wst reads done (later iters)
        #pragma unroll
        for (int u = 0; u < 8; ++u) {
            const int fi = tid + u * 128;
            const int kr = fi >> 6;
            const int cc = (fi & 63) * 4;
            *(float4*)(Wst + kr * 260 + cc) = *(const float4*)(W + (size_t)(kt + kr) * II + cc);
        }
        __syncthreads();
        #pragma unroll 8
        for (int k2 = 0; k2 < 16; ++k2) {
            const float4 xa = *(const float4*)(XsT + (kt + k2) * 36 + r0);
            const float4 xb = *(const float4*)(XsT + (kt + k2) * 36 + r0 + 4);
            const float4 wa = *(const float4*)(Wst + k2 * 260 + c0);
            const float4 wb = *(const float4*)(Wst + k2 * 260 + c0 + 128);
            float xr[8] = {xa.x, xa.y, xa.z, xa.w, xb.x, xb.y, xb.z, xb.w};
            float wc[8] = {wa.x, wa.y, wa.z, wa.w, wb.x, wb.y, wb.z, wb.w};
            #pragma unroll
            for (int a = 0; a < 8; ++a)
                #pragma unroll
                for (int b2 = 0; b2 < 8; ++b2)
                    acc[a][b2] += xr[a] * wc[b2];
        }
    }

    const float4 ba1 = *(const float4*)(bias + c0);
    const float4 ba2 = *(const float4*)(bias + c0 + 128);
    #pragma unroll
    for (int a = 0; a < 8; ++a) {
        float* drow = dst + ((size_t)(bbi * PP + p0 + r0 + a) * LL + l) * II;
        float4 o1 = {acc[a][0] + ba1.x, acc[a][1] + ba1.y, acc[a][2] + ba1.z, acc[a][3] + ba1.w};
        float4 o2 = {acc[a][4] + ba2.x, acc[a][5] + ba2.y, acc[a][6] + ba2.z, acc[a][7] + ba2.w};
        *(float4*)(drow + c0) = o1;
        *(float4*)(drow + c0 + 128) = o2;
    }
}

// ---------------------------------------------------------------------------
// Kernel 2: relation-typed attention, one block per (b, head, 8-pixel tile).
// Uses type-factored qA[i][tj] / vM[ti][j] (L*T instead of L*L matmuls).
// Phased LDS (att-mats -> msg-mats reload) to stay under 64 KB static LDS.
// ---------------------------------------------------------------------------
__global__ __launch_bounds__(256) void k_attn(
    const float* __restrict__ qg, const float* __restrict__ kg, const float* __restrict__ vg,
    const int* __restrict__ mask, const float* __restrict__ prior,
    const float* __restrict__ rel_att, const float* __restrict__ rel_msg,
    float* __restrict__ ao)
{
    __shared__ float sm[13936];
    __shared__ int ty[LL];
    float* As   = sm;            // 4112 floats: [e(4)] * 1028 (att, later msg)
    float* qsT  = sm + 4112;     // 1920: [(l*32+d)*12 + pix]
    float* ksT  = sm + 4112;     // alias of qsT region: [(j*8+pix)*33 + q]
    float* vsT  = sm + 6032;     // 1920
    float* qA   = sm + 7952;     // 2880: [((pix*5+i)*2+tj)*36 + q]
    float* vM   = sm + 10832;    // 2880: [((pix*2+ti)*5+j)*36 + c]
    float* attS = sm + 13712;    // 224:  [pix*28 + i*5 + j]

    const int tid = threadIdx.x;
    const int bm  = blockIdx.x >> 7;   // b*M + m
    const int pt  = blockIdx.x & 127;
    const int bbi = bm >> 3;
    const int m   = bm & 7;
    const int p0  = pt * 8;

    if (tid < LL) ty[tid] = (int)prior[(size_t)(bbi * LL + tid) * (PP * 3) + 2];

    // stage rel_att (4 e-matrices for this head) + q,v slices
    for (int fi = tid; fi < 4096; fi += 256) {
        const int e = fi >> 10, r2 = fi & 1023;
        As[e * 1028 + r2] = rel_att[(size_t)(e * MM + m) * 1024 + r2];
    }
    for (int fi = tid; fi < 1280; fi += 256) {
        const int d = fi & 31, l2 = (fi >> 5) % 5, pix = fi / 160;
        const size_t g = ((size_t)(bbi * PP + p0 + pix) * LL + l2) * II + m * DD + d;
        qsT[(l2 * 32 + d) * 12 + pix] = qg[g];
        vsT[(l2 * 32 + d) * 12 + pix] = vg[g];
    }
    __syncthreads();

    // phase 1a: qA[i][tj] = q_i @ A[ty(i)*2+tj]
    for (int jd = tid; jd < 160; jd += 256) {
        const int pixo = jd & 1, qq = (jd >> 1) & 7, tj = (jd >> 4) & 1, i = jd >> 5;
        const int q0 = qq * 4, pix0 = pixo * 4;
        const float* A = As + (ty[i] * 2 + tj) * 1028;
        float4 acc[4];
        #pragma unroll
        for (int pp = 0; pp < 4; ++pp) acc[pp] = make_float4(0.f, 0.f, 0.f, 0.f);
        for (int p = 0; p < 32; ++p) {
            const float4 a4 = *(const float4*)(A + p * 32 + q0);
            const float4 s  = *(const float4*)(qsT + (i * 32 + p) * 12 + pix0);
            acc[0].x += s.x * a4.x; acc[0].y += s.x * a4.y; acc[0].z += s.x * a4.z; acc[0].w += s.x * a4.w;
            acc[1].x += s.y * a4.x; acc[1].y += s.y * a4.y; acc[1].z += s.y * a4.z; acc[1].w += s.y * a4.w;
            acc[2].x += s.z * a4.x; acc[2].y += s.z * a4.y; acc[2].z += s.z * a4.z; acc[2].w += s.z * a4.w;
            acc[3].x += s.w * a4.x; acc[3].y += s.w * a4.y; acc[3].z += s.w * a4.z; acc[3].w += s.w * a4.w;
        }
        #pragma unroll
        for (int pp = 0; pp < 4; ++pp) {
            const int pix = pix0 + pp;
            *(float4*)(qA + ((pix * 5 + i) * 2 + tj) * 36 + q0) = acc[pp];
        }
    }
    __syncthreads();

    // reload: As <- rel_msg ; ksT (aliases dead qsT)
    for (int fi = tid; fi < 4096; fi += 256) {
        const int e = fi >> 10, r2 = fi & 1023;
        As[e * 1028 + r2] = rel_msg[(size_t)(e * MM + m) * 1024 + r2];
    }
    for (int fi = tid; fi < 1280; fi += 256) {
        const int d = fi & 31, l2 = (fi >> 5) % 5, pix = fi / 160;
        const size_t g = ((size_t)(bbi * PP + p0 + pix) * LL + l2) * II + m * DD + d;
        ksT[(l2 * 8 + pix) * 33 + d] = kg[g];
    }
    __syncthreads();

    // phase 1b: vM[ti][j] = v_j @ Msg[ti*2+ty(j)]
    for (int jd = tid; jd < 160; jd += 256) {
        const int pixo = jd & 1, qq = (jd >> 1) & 7, ti = (jd >> 4) & 1, j = jd >> 5;
        const int q0 = qq * 4, pix0 = pixo * 4;
        const float* A = As + (ti * 2 + ty[j]) * 1028;
        float4 acc[4];
        #pragma unroll
        for (int pp = 0; pp < 4; ++pp) acc[pp] = make_float4(0.f, 0.f, 0.f, 0.f);
        for (int p = 0; p < 32; ++p) {
            const float4 a4 = *(const float4*)(A + p * 32 + q0);
            const float4 s  = *(const float4*)(vsT + (j * 32 + p) * 12 + pix0);
            acc[0].x += s.x * a4.x; acc[0].y += s.x * a4.y; acc[0].z += s.x * a4.z; acc[0].w += s.x * a4.w;
            acc[1].x += s.y * a4.x; acc[1].y += s.y * a4.y; acc[1].z += s.y * a4.z; acc[1].w += s.y * a4.w;
            acc[2].x += s.z * a4.x; acc[2].y += s.z * a4.y; acc[2].z += s.z * a4.z; acc[2].w += s.z * a4.w;
            acc[3].x += s.w * a4.x; acc[3].y += s.w * a4.y; acc[3].z += s.w * a4.z; acc[3].w += s.w * a4.w;
        }
        #pragma unroll
        for (int pp = 0; pp < 4; ++pp) {
            const int pix = pix0 + pp;
            *(float4*)(vM + ((pix * 2 + ti) * 5 + j) * 36 + q0) = acc[pp];
        }
    }
    __syncthreads();

    // phase 2: logits
    for (int jd = tid; jd < 200; jd += 256) {
        const int j = jd % 5, i = (jd / 5) % 5, pix = jd / 25;
        const float* qrow = qA + ((pix * 5 + i) * 2 + ty[j]) * 36;
        const float* krow = ksT + (j * 8 + pix) * 33;
        float acc = 0.f;
        #pragma unroll
        for (int q2 = 0; q2 < 8; ++q2) {
            const float4 qa = *(const float4*)(qrow + q2 * 4);
            acc += qa.x * krow[q2 * 4 + 0] + qa.y * krow[q2 * 4 + 1]
                 + qa.z * krow[q2 * 4 + 2] + qa.w * krow[q2 * 4 + 3];
        }
        acc *= SCALE;
        const int mv = mask[((size_t)(bbi * PP + p0 + pix) * LL + i) * LL + j];
        attS[pix * 28 + i * 5 + j] = mv ? acc : -1e9f;
    }
    __syncthreads();

    // phase 3: softmax over j
    if (tid < 40) {
        const int i = tid % 5, pix = tid / 5;
        float* row = attS + pix * 28 + i * 5;
        float mx = row[0];
        #pragma unroll
        for (int j = 1; j < 5; ++j) mx = fmaxf(mx, row[j]);
        float ex[5], s = 0.f;
        #pragma unroll
        for (int j = 0; j < 5; ++j) { ex[j] = __expf(row[j] - mx); s += ex[j]; }
        const float rs = 1.0f / s;
        #pragma unroll
        for (int j = 0; j < 5; ++j) row[j] = ex[j] * rs;
    }
    __syncthreads();

    // phase 4: out_i = sum_j att[i][j] * vM[ty(i)][j]
    for (int jd = tid; jd < 320; jd += 256) {
        const int cq = jd & 7, i = (jd >> 3) % 5, pix = jd / 40;
        const int ti = ty[i], c0 = cq * 4;
        float4 o = make_float4(0.f, 0.f, 0.f, 0.f);
        #pragma unroll
        for (int j = 0; j < 5; ++j) {
            const float aw = attS[pix * 28 + i * 5 + j];
            const float4 vm = *(const float4*)(vM + ((pix * 2 + ti) * 5 + j) * 36 + c0);
            o.x += aw * vm.x; o.y += aw * vm.y; o.z += aw * vm.z; o.w += aw * vm.w;
        }
        *(float4*)(ao + ((size_t)(bbi * PP + p0 + pix) * LL + i) * II + m * DD + c0) = o;
    }
}

// ---------------------------------------------------------------------------
// Kernel 3: output projection + final [B,L,H,W,C] transpose.
// Grid: 20 x 32 = 640 blocks, 128 thr. Same GEMM structure as kernel 1.
// ---------------------------------------------------------------------------
__global__ __launch_bounds__(128) void k_out(
    const float* __restrict__ ao, const float* __restrict__ prior,
    const float* __restrict__ Wa, const float* __restrict__ ba,
    float* __restrict__ out)
{
    __shared__ float XsT[256 * 36];
    __shared__ float Wst[16 * 260];

    const int tid = threadIdx.x;
    const int bl  = blockIdx.x >> 5;
    const int rt  = blockIdx.x & 31;
    const int bbi = bl / LL;
    const int l   = bl - bbi * LL;
    const int p0  = rt * 32;
    const int t   = (int)prior[(size_t)bl * (PP * 3) + 2];

    const int r  = tid >> 2;
    const int jj = tid & 3;
    const float* arow = ao + ((size_t)(bbi * PP + p0 + r) * LL + l) * II;
    #pragma unroll
    for (int u = 0; u < 16; ++u) {
        const int c = (jj + 4 * u) * 4;
        const float4 av = *(const float4*)(arow + c);
        XsT[(c + 0) * 36 + r] = av.x;
        XsT[(c + 1) * 36 + r] = av.y;
        XsT[(c + 2) * 36 + r] = av.z;
        XsT[(c + 3) * 36 + r] = av.w;
    }

    const float* W   = Wa + (size_t)t * II * CC;
    const float* bias = ba + t * CC;

    const int rg = tid >> 5;
    const int cg = tid & 31;
    const int r0 = rg * 8;
    const int c0 = cg * 4;

    float acc[8][8];
    #pragma unroll
    for (int a = 0; a < 8; ++a)
        #pragma unroll
        for (int b2 = 0; b2 < 8; ++b2) acc[a][b2] = 0.f;

    for (int kt = 0; kt < 256; kt += 16) {
        __syncthreads();
        #pragma unroll
        for (int u = 0; u < 8; ++u) {
            const int fi = tid + u * 128;
            const int kr = fi >> 6;
            const int cc = (fi & 63) * 4;
            *(float4*)(Wst + kr * 260 + cc) = *(const float4*)(W + (size_t)(kt + kr) * CC + cc);
        }
        __syncthreads();
        #pragma unroll 8
        for (int k2 = 0; k2 < 16; ++k2) {
            const float4 xa = *(const float4*)(XsT + (kt + k2) * 36 + r0);
            const float4 xb = *(const float4*)(XsT + (kt + k2) * 36 + r0 + 4);
            const float4 wa = *(const float4*)(Wst + k2 * 260 + c0);
            const float4 wb = *(const float4*)(Wst + k2 * 260 + c0 + 128);
            float xr[8] = {xa.x, xa.y, xa.z, xa.w, xb.x, xb.y, xb.z, xb.w};
            float wc[8] = {wa.x, wa.y, wa.z, wa.w, wb.x, wb.y, wb.z, wb.w};
            #pragma unroll
            for (int a = 0; a < 8; ++a)
                #pragma unroll
                for (int b2 = 0; b2 < 8; ++b2)
                    acc[a][b2] += xr[a] * wc[b2];
        }
    }

    const float4 ba1 = *(const float4*)(bias + c0);
    const float4 ba2 = *(const float4*)(bias + c0 + 128);
    #pragma unroll
    for (int a = 0; a < 8; ++a) {
        float* drow = out + ((size_t)(bbi * LL + l) * PP + p0 + r0 + a) * CC;
        float4 o1 = {acc[a][0] + ba1.x, acc[a][1] + ba1.y, acc[a][2] + ba1.z, acc[a][3] + ba1.w};
        float4 o2 = {acc[a][4] + ba2.x, acc[a][5] + ba2.y, acc[a][6] + ba2.z, acc[a][7] + ba2.w};
        *(float4*)(drow + c0) = o1;
        *(float4*)(drow + c0 + 128) = o2;
    }
}

// ---------------------------------------------------------------------------
extern "C" void kernel_launch(void* const* d_in, const int* in_sizes, int n_in,
                              void* d_out, int out_size, void* d_ws, size_t ws_size,
                              hipStream_t stream) {
    const float* x       = (const float*)d_in[0];
    const int*   mask    = (const int*)d_in[1];
    const float* prior   = (const float*)d_in[2];
    const float* lnw     = (const float*)d_in[3];
    const float* lnb     = (const float*)d_in[4];
    const float* Wq      = (const float*)d_in[5];
    const float* bq      = (const float*)d_in[6];
    const float* Wk      = (const float*)d_in[7];
    const float* bk      = (const float*)d_in[8];
    const float* Wv      = (const float*)d_in[9];
    const float* bv      = (const float*)d_in[10];
    const float* Wa      = (const float*)d_in[11];
    const float* ba      = (const float*)d_in[12];
    const float* rel_att = (const float*)d_in[13];
    const float* rel_msg = (const float*)d_in[14];
    float* out = (float*)d_out;

    const size_t NTOK = (size_t)BB * PP * LL * II;   // 5,242,880 floats
    float* q  = (float*)d_ws;
    float* kk = q + NTOK;
    float* vv = kk + NTOK;
    float* ao = vv + NTOK;

    hipLaunchKernelGGL(k_ln_qkv, dim3(1920), dim3(128), 0, stream,
                       x, prior, lnw, lnb, Wq, bq, Wk, bk, Wv, bv, q, kk, vv);
    hipLaunchKernelGGL(k_attn, dim3(4096), dim3(256), 0, stream,
                       q, kk, vv, mask, prior, rel_att, rel_msg, ao);
    hipLaunchKernelGGL(k_out, dim3(640), dim3(128), 0, stream,
                       ao, prior, Wa, ba, out);
}

// Round 2
// 219.040 us; speedup vs baseline: 1.5990x; 1.5990x over previous
//
#include <hip/hip_runtime.h>
#include <hip/hip_bf16.h>
#include <math.h>

#define BB 4
#define LL 5
#define HSZ 32
#define WSZ 32
#define PP (HSZ*WSZ)   // 1024
#define CC 256
#define MM 8
#define DD 32
#define II 256
#define TT 2
#define SCALE 0.17677669529663687f  // 1/sqrt(32)

typedef short bf16x8 __attribute__((ext_vector_type(8)));
typedef float f32x4 __attribute__((ext_vector_type(4)));

static __device__ __forceinline__ ushort f2bf(float f) {
    unsigned u = __float_as_uint(f);
    unsigned r = (u + 0x7fffu + ((u >> 16) & 1u)) >> 16;   // RNE
    return (ushort)r;
}

// ---------------------------------------------------------------------------
// k_convert: pack fp32 weights into bf16 MFMA B-fragment order.
// Pack layout: [(mat*T + t)][nt(16)][kt(8)][lane(64)][j(8)]  (65536 elem / (mat,t))
//   B-frag for 16x16x32: lane holds B[k = kt*32 + (lane>>4)*8 + j][n = nt*16 + (lane&15)]
// 65536 j-groups total (49152 qkv + 16384 Wa), 1 thread per group.
// ---------------------------------------------------------------------------
__global__ __launch_bounds__(256) void k_convert(
    const float* __restrict__ Wq, const float* __restrict__ Wk,
    const float* __restrict__ Wv, const float* __restrict__ Wa,
    ushort* __restrict__ packQKV, ushort* __restrict__ packA)
{
    const int gi = blockIdx.x * 256 + threadIdx.x;   // 0..65535
    const float* src;
    ushort* dst;
    int sub, t;
    if (gi < 49152) {
        const int mt_idx = gi >> 13;          // mat*2 + t, 0..5
        const int mat = mt_idx >> 1;
        t = mt_idx & 1;
        sub = gi & 8191;
        src = (mat == 0) ? Wq : (mat == 1) ? Wk : Wv;
        dst = packQKV + (size_t)gi * 8;
    } else {
        const int gj = gi - 49152;
        t = gj >> 13;
        sub = gj & 8191;
        src = Wa;
        dst = packA + (size_t)gj * 8;
    }
    const int nt = sub >> 9;
    const int kt = (sub >> 6) & 7;
    const int lane = sub & 63;
    const int k0 = kt * 32 + (lane >> 4) * 8;
    const int n  = nt * 16 + (lane & 15);
    const float* w = src + (size_t)t * 65536;
    ushort h[8];
    #pragma unroll
    for (int j = 0; j < 8; ++j) h[j] = f2bf(w[(size_t)(k0 + j) * 256 + n]);
    uint4 o;
    o.x = (unsigned)h[0] | ((unsigned)h[1] << 16);
    o.y = (unsigned)h[2] | ((unsigned)h[3] << 16);
    o.z = (unsigned)h[4] | ((unsigned)h[5] << 16);
    o.w = (unsigned)h[6] | ((unsigned)h[7] << 16);
    *(uint4*)dst = o;
}

// ---------------------------------------------------------------------------
// k_ln_qkv_mfma: fused LayerNorm + per-type q/k/v projection via bf16 MFMA.
// Grid 640 = 20 (b,l) x 32 pixel-tiles of 32. Block 256 thr (4 waves).
// A-pack LDS layout: [mt(2)][kt(8)][lane(64)][j(8)] bf16 = 16 KB, so that
// ds_read_b128 at ((mt*8+kt)*64+lane)*16 is lane-contiguous (conflict-free).
// B-frags loaded straight from packed global (L2-resident), no LDS, no
// barrier in K-loop. Wave w covers cols [64w, 64w+64).
// ---------------------------------------------------------------------------
__global__ __launch_bounds__(256) void k_ln_qkv_mfma(
    const float* __restrict__ x, const float* __restrict__ prior,
    const float* __restrict__ lnw, const float* __restrict__ lnb,
    const ushort* __restrict__ packQKV,
    const float* __restrict__ bq, const float* __restrict__ bk, const float* __restrict__ bv,
    float* __restrict__ outq, float* __restrict__ outk, float* __restrict__ outv)
{
    __shared__ ushort Apack[2 * 8 * 64 * 8];   // 16 KB

    const int tid = threadIdx.x;
    const int bl  = blockIdx.x >> 5;
    const int pt  = blockIdx.x & 31;
    const int bbi = bl / LL;
    const int l   = bl - bbi * LL;
    const int p0  = pt * 32;
    const int t   = (int)prior[(size_t)bl * (PP * 3) + 2];

    // ---- LayerNorm: 8 threads per pixel row, 32 channels each ----
    const int r  = tid >> 3;     // 0..31
    const int jj = tid & 7;
    const float* xrow = x + ((size_t)bl * PP + p0 + r) * CC;
    float4 xv[8];
    float s1 = 0.f, s2 = 0.f;
    #pragma unroll
    for (int u = 0; u < 8; ++u) {
        xv[u] = *(const float4*)(xrow + jj * 32 + u * 4);
        s1 += xv[u].x + xv[u].y + xv[u].z + xv[u].w;
        s2 += xv[u].x * xv[u].x + xv[u].y * xv[u].y + xv[u].z * xv[u].z + xv[u].w * xv[u].w;
    }
    s1 += __shfl_xor(s1, 1); s1 += __shfl_xor(s1, 2); s1 += __shfl_xor(s1, 4);
    s2 += __shfl_xor(s2, 1); s2 += __shfl_xor(s2, 2); s2 += __shfl_xor(s2, 4);
    const float mu   = s1 * (1.0f / 256.0f);
    const float var  = s2 * (1.0f / 256.0f) - mu * mu;
    const float rstd = rsqrtf(var + 1e-5f);

    // ---- pack normalized bf16 rows into A-fragment order ----
    const int mt_r = r >> 4, rm = r & 15;
    #pragma unroll
    for (int u = 0; u < 8; ++u) {
        const int c0 = jj * 32 + u * 4;
        const float4 g  = *(const float4*)(lnw + c0);
        const float4 bt = *(const float4*)(lnb + c0);
        const ushort h0 = f2bf((xv[u].x - mu) * rstd * g.x + bt.x);
        const ushort h1 = f2bf((xv[u].y - mu) * rstd * g.y + bt.y);
        const ushort h2 = f2bf((xv[u].z - mu) * rstd * g.z + bt.z);
        const ushort h3 = f2bf((xv[u].w - mu) * rstd * g.w + bt.w);
        uint2 w2;
        w2.x = (unsigned)h0 | ((unsigned)h1 << 16);
        w2.y = (unsigned)h2 | ((unsigned)h3 << 16);
        const int lsub = rm + ((u >> 1) << 4);      // (c0>>3)&3 == u>>1
        const int j0   = (u & 1) * 4;               // c0&7
        *(uint2*)&Apack[(((mt_r * 8 + jj) * 64 + lsub) << 3) + j0] = w2;
    }
    __syncthreads();

    // ---- MFMA GEMM ----
    const int wv = tid >> 6, lane = tid & 63;
    bf16x8 afr[2][8];
    #pragma unroll
    for (int mt = 0; mt < 2; ++mt)
        #pragma unroll
        for (int kt = 0; kt < 8; ++kt)
            afr[mt][kt] = *(const bf16x8*)&Apack[(((mt * 8 + kt) * 64 + lane) << 3)];

    const int cl = lane & 15, rq = lane >> 4;

    #pragma unroll 1
    for (int mat = 0; mat < 3; ++mat) {
        const ushort* Bp = packQKV + ((size_t)(mat * TT + t)) * 65536;
        const float* bias = ((mat == 0) ? bq : (mat == 1) ? bk : bv) + t * II;
        float* dst = (mat == 0) ? outq : (mat == 1) ? outk : outv;

        f32x4 acc[2][4];
        #pragma unroll
        for (int mt = 0; mt < 2; ++mt)
            #pragma unroll
            for (int nn = 0; nn < 4; ++nn)
                acc[mt][nn] = (f32x4){0.f, 0.f, 0.f, 0.f};

        #pragma unroll
        for (int kt = 0; kt < 8; ++kt) {
            #pragma unroll
            for (int nn = 0; nn < 4; ++nn) {
                const int ntg = wv * 4 + nn;
                const bf16x8 bfr = *(const bf16x8*)&Bp[(((ntg * 8 + kt) * 64 + lane) << 3)];
                acc[0][nn] = __builtin_amdgcn_mfma_f32_16x16x32_bf16(afr[0][kt], bfr, acc[0][nn], 0, 0, 0);
                acc[1][nn] = __builtin_amdgcn_mfma_f32_16x16x32_bf16(afr[1][kt], bfr, acc[1][nn], 0, 0, 0);
            }
        }

        #pragma unroll
        for (int nn = 0; nn < 4; ++nn) {
            const int col = wv * 64 + nn * 16 + cl;
            const float bb_ = bias[col];
            #pragma unroll
            for (int mt = 0; mt < 2; ++mt) {
                const int row0 = p0 + mt * 16 + rq * 4;
                #pragma unroll
                for (int r2 = 0; r2 < 4; ++r2) {
                    dst[((size_t)(bbi * PP + row0 + r2) * LL + l) * II + col] = acc[mt][nn][r2] + bb_;
                }
            }
        }
    }
}

// ---------------------------------------------------------------------------
// k_out_mfma: output projection + final transpose via bf16 MFMA.
// Same structure as k_ln_qkv_mfma, single matrix (Wa), input rows from ao.
// ---------------------------------------------------------------------------
__global__ __launch_bounds__(256) void k_out_mfma(
    const float* __restrict__ ao, const float* __restrict__ prior,
    const ushort* __restrict__ packA, const float* __restrict__ ba,
    float* __restrict__ out)
{
    __shared__ ushort Apack[2 * 8 * 64 * 8];   // 16 KB

    const int tid = threadIdx.x;
    const int bl  = blockIdx.x >> 5;
    const int pt  = blockIdx.x & 31;
    const int bbi = bl / LL;
    const int l   = bl - bbi * LL;
    const int p0  = pt * 32;
    const int t   = (int)prior[(size_t)bl * (PP * 3) + 2];

    const int r  = tid >> 3;
    const int jj = tid & 7;
    const float* arow = ao + ((size_t)(bbi * PP + p0 + r) * LL + l) * II;
    const int mt_r = r >> 4, rm = r & 15;
    #pragma unroll
    for (int u = 0; u < 8; ++u) {
        const int c0 = jj * 32 + u * 4;
        const float4 av = *(const float4*)(arow + c0);
        uint2 w2;
        w2.x = (unsigned)f2bf(av.x) | ((unsigned)f2bf(av.y) << 16);
        w2.y = (unsigned)f2bf(av.z) | ((unsigned)f2bf(av.w) << 16);
        const int lsub = rm + ((u >> 1) << 4);
        const int j0   = (u & 1) * 4;
        *(uint2*)&Apack[(((mt_r * 8 + jj) * 64 + lsub) << 3) + j0] = w2;
    }
    __syncthreads();

    const int wv = tid >> 6, lane = tid & 63;
    bf16x8 afr[2][8];
    #pragma unroll
    for (int mt = 0; mt < 2; ++mt)
        #pragma unroll
        for (int kt = 0; kt < 8; ++kt)
            afr[mt][kt] = *(const bf16x8*)&Apack[(((mt * 8 + kt) * 64 + lane) << 3)];

    const ushort* Bp = packA + (size_t)t * 65536;
    const float* bias = ba + t * CC;

    f32x4 acc[2][4];
    #pragma unroll
    for (int mt = 0; mt < 2; ++mt)
        #pragma unroll
        for (int nn = 0; nn < 4; ++nn)
            acc[mt][nn] = (f32x4){0.f, 0.f, 0.f, 0.f};

    #pragma unroll
    for (int kt = 0; kt < 8; ++kt) {
        #pragma unroll
        for (int nn = 0; nn < 4; ++nn) {
            const int ntg = wv * 4 + nn;
            const bf16x8 bfr = *(const bf16x8*)&Bp[(((ntg * 8 + kt) * 64 + lane) << 3)];
            acc[0][nn] = __builtin_amdgcn_mfma_f32_16x16x32_bf16(afr[0][kt], bfr, acc[0][nn], 0, 0, 0);
            acc[1][nn] = __builtin_amdgcn_mfma_f32_16x16x32_bf16(afr[1][kt], bfr, acc[1][nn], 0, 0, 0);
        }
    }

    const int cl = lane & 15, rq = lane >> 4;
    #pragma unroll
    for (int nn = 0; nn < 4; ++nn) {
        const int col = wv * 64 + nn * 16 + cl;
        const float bb_ = bias[col];
        #pragma unroll
        for (int mt = 0; mt < 2; ++mt) {
            const int row0 = p0 + mt * 16 + rq * 4;
            #pragma unroll
            for (int r2 = 0; r2 < 4; ++r2) {
                out[((size_t)(bbi * LL + l) * PP + row0 + r2) * CC + col] = acc[mt][nn][r2] + bb_;
            }
        }
    }
}

// ---------------------------------------------------------------------------
// Kernel 2: relation-typed attention (unchanged fp32 path).
// ---------------------------------------------------------------------------
__global__ __launch_bounds__(256) void k_attn(
    const float* __restrict__ qg, const float* __restrict__ kg, const float* __restrict__ vg,
    const int* __restrict__ mask, const float* __restrict__ prior,
    const float* __restrict__ rel_att, const float* __restrict__ rel_msg,
    float* __restrict__ ao)
{
    __shared__ float sm[13936];
    __shared__ int ty[LL];
    float* As   = sm;
    float* qsT  = sm + 4112;
    float* ksT  = sm + 4112;
    float* vsT  = sm + 6032;
    float* qA   = sm + 7952;
    float* vM   = sm + 10832;
    float* attS = sm + 13712;

    const int tid = threadIdx.x;
    const int bm  = blockIdx.x >> 7;
    const int pt  = blockIdx.x & 127;
    const int bbi = bm >> 3;
    const int m   = bm & 7;
    const int p0  = pt * 8;

    if (tid < LL) ty[tid] = (int)prior[(size_t)(bbi * LL + tid) * (PP * 3) + 2];

    for (int fi = tid; fi < 4096; fi += 256) {
        const int e = fi >> 10, r2 = fi & 1023;
        As[e * 1028 + r2] = rel_att[(size_t)(e * MM + m) * 1024 + r2];
    }
    for (int fi = tid; fi < 1280; fi += 256) {
        const int d = fi & 31, l2 = (fi >> 5) % 5, pix = fi / 160;
        const size_t g = ((size_t)(bbi * PP + p0 + pix) * LL + l2) * II + m * DD + d;
        qsT[(l2 * 32 + d) * 12 + pix] = qg[g];
        vsT[(l2 * 32 + d) * 12 + pix] = vg[g];
    }
    __syncthreads();

    for (int jd = tid; jd < 160; jd += 256) {
        const int pixo = jd & 1, qq = (jd >> 1) & 7, tj = (jd >> 4) & 1, i = jd >> 5;
        const int q0 = qq * 4, pix0 = pixo * 4;
        const float* A = As + (ty[i] * 2 + tj) * 1028;
        float4 acc[4];
        #pragma unroll
        for (int pp = 0; pp < 4; ++pp) acc[pp] = make_float4(0.f, 0.f, 0.f, 0.f);
        for (int p = 0; p < 32; ++p) {
            const float4 a4 = *(const float4*)(A + p * 32 + q0);
            const float4 s  = *(const float4*)(qsT + (i * 32 + p) * 12 + pix0);
            acc[0].x += s.x * a4.x; acc[0].y += s.x * a4.y; acc[0].z += s.x * a4.z; acc[0].w += s.x * a4.w;
            acc[1].x += s.y * a4.x; acc[1].y += s.y * a4.y; acc[1].z += s.y * a4.z; acc[1].w += s.y * a4.w;
            acc[2].x += s.z * a4.x; acc[2].y += s.z * a4.y; acc[2].z += s.z * a4.z; acc[2].w += s.z * a4.w;
            acc[3].x += s.w * a4.x; acc[3].y += s.w * a4.y; acc[3].z += s.w * a4.z; acc[3].w += s.w * a4.w;
        }
        #pragma unroll
        for (int pp = 0; pp < 4; ++pp) {
            const int pix = pix0 + pp;
            *(float4*)(qA + ((pix * 5 + i) * 2 + tj) * 36 + q0) = acc[pp];
        }
    }
    __syncthreads();

    for (int fi = tid; fi < 4096; fi += 256) {
        const int e = fi >> 10, r2 = fi & 1023;
        As[e * 1028 + r2] = rel_msg[(size_t)(e * MM + m) * 1024 + r2];
    }
    for (int fi = tid; fi < 1280; fi += 256) {
        const int d = fi & 31, l2 = (fi >> 5) % 5, pix = fi / 160;
        const size_t g = ((size_t)(bbi * PP + p0 + pix) * LL + l2) * II + m * DD + d;
        ksT[(l2 * 8 + pix) * 33 + d] = kg[g];
    }
    __syncthreads();

    for (int jd = tid; jd < 160; jd += 256) {
        const int pixo = jd & 1, qq = (jd >> 1) & 7, ti = (jd >> 4) & 1, j = jd >> 5;
        const int q0 = qq * 4, pix0 = pixo * 4;
        const float* A = As + (ti * 2 + ty[j]) * 1028;
        float4 acc[4];
        #pragma unroll
        for (int pp = 0; pp < 4; ++pp) acc[pp] = make_float4(0.f, 0.f, 0.f, 0.f);
        for (int p = 0; p < 32; ++p) {
            const float4 a4 = *(const float4*)(A + p * 32 + q0);
            const float4 s  = *(const float4*)(vsT + (j * 32 + p) * 12 + pix0);
            acc[0].x += s.x * a4.x; acc[0].y += s.x * a4.y; acc[0].z += s.x * a4.z; acc[0].w += s.x * a4.w;
            acc[1].x += s.y * a4.x; acc[1].y += s.y * a4.y; acc[1].z += s.y * a4.z; acc[1].w += s.y * a4.w;
            acc[2].x += s.z * a4.x; acc[2].y += s.z * a4.y; acc[2].z += s.z * a4.z; acc[2].w += s.z * a4.w;
            acc[3].x += s.w * a4.x; acc[3].y += s.w * a4.y; acc[3].z += s.w * a4.z; acc[3].w += s.w * a4.w;
        }
        #pragma unroll
        for (int pp = 0; pp < 4; ++pp) {
            const int pix = pix0 + pp;
            *(float4*)(vM + ((pix * 2 + ti) * 5 + j) * 36 + q0) = acc[pp];
        }
    }
    __syncthreads();

    for (int jd = tid; jd < 200; jd += 256) {
        const int j = jd % 5, i = (jd / 5) % 5, pix = jd / 25;
        const float* qrow = qA + ((pix * 5 + i) * 2 + ty[j]) * 36;
        const float* krow = ksT + (j * 8 + pix) * 33;
        float acc = 0.f;
        #pragma unroll
        for (int q2 = 0; q2 < 8; ++q2) {
            const float4 qa = *(const float4*)(qrow + q2 * 4);
            acc += qa.x * krow[q2 * 4 + 0] + qa.y * krow[q2 * 4 + 1]
                 + qa.z * krow[q2 * 4 + 2] + qa.w * krow[q2 * 4 + 3];
        }
        acc *= SCALE;
        const int mv = mask[((size_t)(bbi * PP + p0 + pix) * LL + i) * LL + j];
        attS[pix * 28 + i * 5 + j] = mv ? acc : -1e9f;
    }
    __syncthreads();

    if (tid < 40) {
        const int i = tid % 5, pix = tid / 5;
        float* row = attS + pix * 28 + i * 5;
        float mx = row[0];
        #pragma unroll
        for (int j = 1; j < 5; ++j) mx = fmaxf(mx, row[j]);
        float ex[5], s = 0.f;
        #pragma unroll
        for (int j = 0; j < 5; ++j) { ex[j] = __expf(row[j] - mx); s += ex[j]; }
        const float rs = 1.0f / s;
        #pragma unroll
        for (int j = 0; j < 5; ++j) row[j] = ex[j] * rs;
    }
    __syncthreads();

    for (int jd = tid; jd < 320; jd += 256) {
        const int cq = jd & 7, i = (jd >> 3) % 5, pix = jd / 40;
        const int ti = ty[i], c0 = cq * 4;
        float4 o = make_float4(0.f, 0.f, 0.f, 0.f);
        #pragma unroll
        for (int j = 0; j < 5; ++j) {
            const float aw = attS[pix * 28 + i * 5 + j];
            const float4 vm = *(const float4*)(vM + ((pix * 2 + ti) * 5 + j) * 36 + c0);
            o.x += aw * vm.x; o.y += aw * vm.y; o.z += aw * vm.z; o.w += aw * vm.w;
        }
        *(float4*)(ao + ((size_t)(bbi * PP + p0 + pix) * LL + i) * II + m * DD + c0) = o;
    }
}

// ---------------------------------------------------------------------------
extern "C" void kernel_launch(void* const* d_in, const int* in_sizes, int n_in,
                              void* d_out, int out_size, void* d_ws, size_t ws_size,
                              hipStream_t stream) {
    const float* x       = (const float*)d_in[0];
    const int*   mask    = (const int*)d_in[1];
    const float* prior   = (const float*)d_in[2];
    const float* lnw     = (const float*)d_in[3];
    const float* lnb     = (const float*)d_in[4];
    const float* Wq      = (const float*)d_in[5];
    const float* bq      = (const float*)d_in[6];
    const float* Wk      = (const float*)d_in[7];
    const float* bk      = (const float*)d_in[8];
    const float* Wv      = (const float*)d_in[9];
    const float* bv      = (const float*)d_in[10];
    const float* Wa      = (const float*)d_in[11];
    const float* ba      = (const float*)d_in[12];
    const float* rel_att = (const float*)d_in[13];
    const float* rel_msg = (const float*)d_in[14];
    float* out = (float*)d_out;

    const size_t NTOK = (size_t)BB * PP * LL * II;   // 5,242,880 floats
    float* q  = (float*)d_ws;
    float* kk = q + NTOK;
    float* vv = kk + NTOK;
    float* ao = vv + NTOK;
    ushort* packQKV = (ushort*)(ao + NTOK);          // 3*2*65536 bf16
    ushort* packWa  = packQKV + 3 * 2 * 65536;       // 2*65536 bf16

    hipLaunchKernelGGL(k_convert, dim3(256), dim3(256), 0, stream,
                       Wq, Wk, Wv, Wa, packQKV, packWa);
    hipLaunchKernelGGL(k_ln_qkv_mfma, dim3(640), dim3(256), 0, stream,
                       x, prior, lnw, lnb, packQKV, bq, bk, bv, q, kk, vv);
    hipLaunchKernelGGL(k_attn, dim3(4096), dim3(256), 0, stream,
                       q, kk, vv, mask, prior, rel_att, rel_msg, ao);
    hipLaunchKernelGGL(k_out_mfma, dim3(640), dim3(256), 0, stream,
                       ao, prior, packWa, ba, out);
}

// Round 3
// 214.410 us; speedup vs baseline: 1.6335x; 1.0216x over previous
//
#include <hip/hip_runtime.h>
#include <hip/hip_bf16.h>
#include <math.h>

#define BB 4
#define LL 5
#define HSZ 32
#define WSZ 32
#define PP (HSZ*WSZ)   // 1024
#define CC 256
#define MM 8
#define DD 32
#define II 256
#define TT 2
#define NTOK (BB*PP*LL*II)   // 5,242,880
#define SCALE 0.17677669529663687f  // 1/sqrt(32)

typedef short bf16x8 __attribute__((ext_vector_type(8)));
typedef float f32x4 __attribute__((ext_vector_type(4)));

static __device__ __forceinline__ ushort f2bf(float f) {
    unsigned u = __float_as_uint(f);
    unsigned r = (u + 0x7fffu + ((u >> 16) & 1u)) >> 16;   // RNE
    return (ushort)r;
}
static __device__ __forceinline__ float bf2f(ushort u) {
    return __uint_as_float(((unsigned)u) << 16);
}

// ---------------------------------------------------------------------------
// k_combine:
//  blocks 0..63: fold rel matrices into projections.
//    blk: p(1)=q/v, t(1), ts(1), m(3).
//    q-side: Weff[t,ts][:,mblk] = Wq[t][:,mblk] @ rel_att[(t*2+ts)*8+m]
//    v-side: Weff[t,ts][:,mblk] = Wv[t][:,mblk] @ rel_msg[(ts*2+t)*8+m]
//    plus folded biases -> bEff[0..1023]=bq_eff[t][ts][n], [1024..2047]=bv_eff.
//  blocks 64..191: plain bf16 pack of Wk (slots 8,9) and Wa (slots 10,11).
//  Pack layout per slot (65536 bf16): [nt(16)][kt(8)][lane(64)][j(8)],
//    B[k=kt*32+(lane>>4)*8+j][n=nt*16+(lane&15)]  (MFMA 16x16x32 B-frag).
// ---------------------------------------------------------------------------
__global__ __launch_bounds__(256) void k_combine(
    const float* __restrict__ Wq, const float* __restrict__ Wv,
    const float* __restrict__ Wk, const float* __restrict__ Wa,
    const float* __restrict__ bq, const float* __restrict__ bv,
    const float* __restrict__ rel_att, const float* __restrict__ rel_msg,
    ushort* __restrict__ packW, float* __restrict__ bEff)
{
    __shared__ float As[1024];
    const int blk = blockIdx.x;
    const int tid = threadIdx.x;
    if (blk < 64) {
        const int p  = blk >> 5;
        const int t  = (blk >> 4) & 1;
        const int ts = (blk >> 3) & 1;
        const int m  = blk & 7;
        const float* A = (p == 0)
            ? rel_att + (size_t)((t * 2 + ts) * 8 + m) * 1024
            : rel_msg + (size_t)((ts * 2 + t) * 8 + m) * 1024;
        for (int i = tid; i < 1024; i += 256) As[i] = A[i];
        __syncthreads();

        const float* W = ((p == 0) ? Wq : Wv) + (size_t)t * 65536;
        const int k = tid;
        float wrow[32];
        #pragma unroll
        for (int u = 0; u < 8; ++u)
            *(float4*)&wrow[u * 4] = *(const float4*)&W[k * 256 + m * 32 + u * 4];

        const int slot = (p == 0 ? 0 : 4) + t * 2 + ts;
        ushort* base = packW + (size_t)slot * 65536;
        const int kt = k >> 5, j = k & 7, lq = ((k >> 3) & 3) * 16;
        #pragma unroll
        for (int q = 0; q < 32; ++q) {
            float acc = 0.f;
            #pragma unroll
            for (int pp = 0; pp < 32; ++pp) acc += wrow[pp] * As[pp * 32 + q];
            const int nt = m * 2 + (q >> 4);
            const int lane = lq + (q & 15);
            base[(size_t)((nt * 8 + kt) * 64 + lane) * 8 + j] = f2bf(acc);
        }
        if (tid < 32) {
            const int q = tid;
            const float* bi = ((p == 0) ? bq : bv) + t * 256 + m * 32;
            float acc = 0.f;
            #pragma unroll
            for (int pp = 0; pp < 32; ++pp) acc += bi[pp] * As[pp * 32 + q];
            bEff[(p ? 1024 : 0) + (t * 2 + ts) * 256 + m * 32 + q] = acc;
        }
    } else {
        const int idx = blk - 64;
        const int which = idx >> 6;              // 0 = Wk, 1 = Wa
        const int gi = (idx & 63) * 256 + tid;   // 0..16383
        const int t = gi >> 13;
        const int sub = gi & 8191;
        const float* src = ((which == 0) ? Wk : Wa) + (size_t)t * 65536;
        const int slot = (which == 0 ? 8 : 10) + t;
        const int nt = sub >> 9, kt = (sub >> 6) & 7, lane = sub & 63;
        const int k0 = kt * 32 + (lane >> 4) * 8;
        const int n  = nt * 16 + (lane & 15);
        ushort h[8];
        #pragma unroll
        for (int j = 0; j < 8; ++j) h[j] = f2bf(src[(size_t)(k0 + j) * 256 + n]);
        uint4 o;
        o.x = (unsigned)h[0] | ((unsigned)h[1] << 16);
        o.y = (unsigned)h[2] | ((unsigned)h[3] << 16);
        o.z = (unsigned)h[4] | ((unsigned)h[5] << 16);
        o.w = (unsigned)h[6] | ((unsigned)h[7] << 16);
        *(uint4*)(packW + (size_t)slot * 65536 + (size_t)sub * 8) = o;
    }
}

// ---------------------------------------------------------------------------
// k_ln_proj: fused LayerNorm + 5 per-type projections (qw0,qw1,k,vm0,vm1),
// bf16 MFMA, bf16 outputs in [B,P,L,I] layout.
// Grid 640 = 20 (b,l) x 32 pixel-tiles, block 256 (4 waves).
// ---------------------------------------------------------------------------
__global__ __launch_bounds__(256) void k_ln_proj(
    const float* __restrict__ x, const float* __restrict__ prior,
    const float* __restrict__ lnw, const float* __restrict__ lnb,
    const ushort* __restrict__ packW, const float* __restrict__ bEff,
    const float* __restrict__ bk,
    ushort* __restrict__ qw0, ushort* __restrict__ qw1, ushort* __restrict__ kkO,
    ushort* __restrict__ vm0, ushort* __restrict__ vm1)
{
    __shared__ ushort Apack[2 * 8 * 64 * 8];   // 16 KB

    const int tid = threadIdx.x;
    const int bl  = blockIdx.x >> 5;
    const int pt  = blockIdx.x & 31;
    const int bbi = bl / LL;
    const int l   = bl - bbi * LL;
    const int p0  = pt * 32;
    const int t   = (int)prior[(size_t)bl * (PP * 3) + 2];

    // ---- LayerNorm ----
    const int r  = tid >> 3;     // 0..31
    const int jj = tid & 7;
    const float* xrow = x + ((size_t)bl * PP + p0 + r) * CC;
    float4 xv[8];
    float s1 = 0.f, s2 = 0.f;
    #pragma unroll
    for (int u = 0; u < 8; ++u) {
        xv[u] = *(const float4*)(xrow + jj * 32 + u * 4);
        s1 += xv[u].x + xv[u].y + xv[u].z + xv[u].w;
        s2 += xv[u].x * xv[u].x + xv[u].y * xv[u].y + xv[u].z * xv[u].z + xv[u].w * xv[u].w;
    }
    s1 += __shfl_xor(s1, 1); s1 += __shfl_xor(s1, 2); s1 += __shfl_xor(s1, 4);
    s2 += __shfl_xor(s2, 1); s2 += __shfl_xor(s2, 2); s2 += __shfl_xor(s2, 4);
    const float mu   = s1 * (1.0f / 256.0f);
    const float var  = s2 * (1.0f / 256.0f) - mu * mu;
    const float rstd = rsqrtf(var + 1e-5f);

    const int mt_r = r >> 4, rm = r & 15;
    #pragma unroll
    for (int u = 0; u < 8; ++u) {
        const int c0 = jj * 32 + u * 4;
        const float4 g  = *(const float4*)(lnw + c0);
        const float4 bt = *(const float4*)(lnb + c0);
        const ushort h0 = f2bf((xv[u].x - mu) * rstd * g.x + bt.x);
        const ushort h1 = f2bf((xv[u].y - mu) * rstd * g.y + bt.y);
        const ushort h2 = f2bf((xv[u].z - mu) * rstd * g.z + bt.z);
        const ushort h3 = f2bf((xv[u].w - mu) * rstd * g.w + bt.w);
        uint2 w2;
        w2.x = (unsigned)h0 | ((unsigned)h1 << 16);
        w2.y = (unsigned)h2 | ((unsigned)h3 << 16);
        const int lsub = rm + ((u >> 1) << 4);
        const int j0   = (u & 1) * 4;
        *(uint2*)&Apack[(((mt_r * 8 + jj) * 64 + lsub) << 3) + j0] = w2;
    }
    __syncthreads();

    const int wv = tid >> 6, lane = tid & 63;
    bf16x8 afr[2][8];
    #pragma unroll
    for (int mt = 0; mt < 2; ++mt)
        #pragma unroll
        for (int kt = 0; kt < 8; ++kt)
            afr[mt][kt] = *(const bf16x8*)&Apack[(((mt * 8 + kt) * 64 + lane) << 3)];

    const int cl = lane & 15, rq = lane >> 4;

    #pragma unroll 1
    for (int mat = 0; mat < 5; ++mat) {
        int slot;
        const float* bias;
        if (mat < 2)       { slot = t * 2 + mat;           bias = bEff + slot * 256; }
        else if (mat == 2) { slot = 8 + t;                 bias = bk + t * 256; }
        else               { slot = 4 + t * 2 + (mat - 3); bias = bEff + 1024 + (t * 2 + (mat - 3)) * 256; }
        ushort* dst = (mat == 0) ? qw0 : (mat == 1) ? qw1 : (mat == 2) ? kkO : (mat == 3) ? vm0 : vm1;
        const ushort* Bp = packW + (size_t)slot * 65536;

        f32x4 acc[2][4];
        #pragma unroll
        for (int mt = 0; mt < 2; ++mt)
            #pragma unroll
            for (int nn = 0; nn < 4; ++nn)
                acc[mt][nn] = (f32x4){0.f, 0.f, 0.f, 0.f};

        #pragma unroll
        for (int kt = 0; kt < 8; ++kt) {
            #pragma unroll
            for (int nn = 0; nn < 4; ++nn) {
                const int ntg = wv * 4 + nn;
                const bf16x8 bfr = *(const bf16x8*)&Bp[(((ntg * 8 + kt) * 64 + lane) << 3)];
                acc[0][nn] = __builtin_amdgcn_mfma_f32_16x16x32_bf16(afr[0][kt], bfr, acc[0][nn], 0, 0, 0);
                acc[1][nn] = __builtin_amdgcn_mfma_f32_16x16x32_bf16(afr[1][kt], bfr, acc[1][nn], 0, 0, 0);
            }
        }

        #pragma unroll
        for (int nn = 0; nn < 4; ++nn) {
            const int col = wv * 64 + nn * 16 + cl;
            const float bb_ = bias[col];
            #pragma unroll
            for (int mt = 0; mt < 2; ++mt) {
                const int row0 = p0 + mt * 16 + rq * 4;
                #pragma unroll
                for (int r2 = 0; r2 < 4; ++r2) {
                    dst[((size_t)(bbi * PP + row0 + r2) * LL + l) * II + col] =
                        f2bf(acc[mt][nn][r2] + bb_);
                }
            }
        }
    }
}

// ---------------------------------------------------------------------------
// k_attn_lite: per-site (b,pixel) attention epilogue. One wave per site.
// Lane holds 4 channels (head m = lane>>3); logits via 8-lane shfl reduce.
// ---------------------------------------------------------------------------
__global__ __launch_bounds__(256) void k_attn_lite(
    const ushort* __restrict__ qw0, const ushort* __restrict__ qw1,
    const ushort* __restrict__ kkI,
    const ushort* __restrict__ vm0, const ushort* __restrict__ vm1,
    const int* __restrict__ mask, const float* __restrict__ prior,
    ushort* __restrict__ ao)
{
    const int tid  = threadIdx.x;
    const int site = blockIdx.x * 4 + (tid >> 6);   // b*1024 + pix, wave-uniform
    const int lane = tid & 63;
    const int b    = site >> 10;
    const int c0   = lane * 4;

    int ty[5];
    #pragma unroll
    for (int l = 0; l < 5; ++l)
        ty[l] = (int)prior[(size_t)(b * 5 + l) * (PP * 3) + 2];

    float qf[2][5][4], kf[5][4], vf[2][5][4];
    #pragma unroll
    for (int l = 0; l < 5; ++l) {
        const size_t base = ((size_t)site * 5 + l) * II + c0;
        const ushort4 q0 = *(const ushort4*)(qw0 + base);
        const ushort4 q1 = *(const ushort4*)(qw1 + base);
        const ushort4 kv = *(const ushort4*)(kkI + base);
        const ushort4 v0 = *(const ushort4*)(vm0 + base);
        const ushort4 v1 = *(const ushort4*)(vm1 + base);
        qf[0][l][0] = bf2f(q0.x); qf[0][l][1] = bf2f(q0.y); qf[0][l][2] = bf2f(q0.z); qf[0][l][3] = bf2f(q0.w);
        qf[1][l][0] = bf2f(q1.x); qf[1][l][1] = bf2f(q1.y); qf[1][l][2] = bf2f(q1.z); qf[1][l][3] = bf2f(q1.w);
        kf[l][0]    = bf2f(kv.x); kf[l][1]    = bf2f(kv.y); kf[l][2]    = bf2f(kv.z); kf[l][3]    = bf2f(kv.w);
        vf[0][l][0] = bf2f(v0.x); vf[0][l][1] = bf2f(v0.y); vf[0][l][2] = bf2f(v0.z); vf[0][l][3] = bf2f(v0.w);
        vf[1][l][0] = bf2f(v1.x); vf[1][l][1] = bf2f(v1.y); vf[1][l][2] = bf2f(v1.z); vf[1][l][3] = bf2f(v1.w);
    }

    #pragma unroll
    for (int i = 0; i < 5; ++i) {
        float lg[5];
        #pragma unroll
        for (int j = 0; j < 5; ++j) {
            const float s0 = qf[0][i][0] * kf[j][0] + qf[0][i][1] * kf[j][1]
                           + qf[0][i][2] * kf[j][2] + qf[0][i][3] * kf[j][3];
            const float s1 = qf[1][i][0] * kf[j][0] + qf[1][i][1] * kf[j][1]
                           + qf[1][i][2] * kf[j][2] + qf[1][i][3] * kf[j][3];
            float s = ty[j] ? s1 : s0;
            s += __shfl_xor(s, 1); s += __shfl_xor(s, 2); s += __shfl_xor(s, 4);
            const int mv = mask[((size_t)site * 5 + i) * 5 + j];
            lg[j] = mv ? s * SCALE : -1e9f;
        }
        float mx = lg[0];
        #pragma unroll
        for (int j = 1; j < 5; ++j) mx = fmaxf(mx, lg[j]);
        float ex[5], sum = 0.f;
        #pragma unroll
        for (int j = 0; j < 5; ++j) { ex[j] = __expf(lg[j] - mx); sum += ex[j]; }
        const float rs = 1.0f / sum;
        float o0 = 0.f, o1 = 0.f, o2 = 0.f, o3 = 0.f;
        #pragma unroll
        for (int j = 0; j < 5; ++j) {
            const float w = ex[j] * rs;
            o0 += w * (ty[i] ? vf[1][j][0] : vf[0][j][0]);
            o1 += w * (ty[i] ? vf[1][j][1] : vf[0][j][1]);
            o2 += w * (ty[i] ? vf[1][j][2] : vf[0][j][2]);
            o3 += w * (ty[i] ? vf[1][j][3] : vf[0][j][3]);
        }
        ushort4 ou;
        ou.x = f2bf(o0); ou.y = f2bf(o1); ou.z = f2bf(o2); ou.w = f2bf(o3);
        *(ushort4*)(ao + ((size_t)site * 5 + i) * II + c0) = ou;
    }
}

// ---------------------------------------------------------------------------
// k_out_mfma: output projection (bf16 ao input) + final transpose, fp32 out.
// ---------------------------------------------------------------------------
__global__ __launch_bounds__(256) void k_out_mfma(
    const ushort* __restrict__ ao, const float* __restrict__ prior,
    const ushort* __restrict__ packW, const float* __restrict__ ba,
    float* __restrict__ out)
{
    __shared__ ushort Apack[2 * 8 * 64 * 8];   // 16 KB

    const int tid = threadIdx.x;
    const int bl  = blockIdx.x >> 5;
    const int pt  = blockIdx.x & 31;
    const int bbi = bl / LL;
    const int l   = bl - bbi * LL;
    const int p0  = pt * 32;
    const int t   = (int)prior[(size_t)bl * (PP * 3) + 2];

    const int r  = tid >> 3;
    const int jj = tid & 7;
    const ushort* arow = ao + ((size_t)(bbi * PP + p0 + r) * LL + l) * II;
    const int mt_r = r >> 4, rm = r & 15;
    #pragma unroll
    for (int g = 0; g < 4; ++g) {
        const uint4 v4 = *(const uint4*)(arow + jj * 32 + g * 8);
        *(uint4*)&Apack[(((mt_r * 8 + jj) * 64 + (rm + g * 16)) << 3)] = v4;
    }
    __syncthreads();

    const int wv = tid >> 6, lane = tid & 63;
    bf16x8 afr[2][8];
    #pragma unroll
    for (int mt = 0; mt < 2; ++mt)
        #pragma unroll
        for (int kt = 0; kt < 8; ++kt)
            afr[mt][kt] = *(const bf16x8*)&Apack[(((mt * 8 + kt) * 64 + lane) << 3)];

    const ushort* Bp = packW + (size_t)(10 + t) * 65536;
    const float* bias = ba + t * CC;

    f32x4 acc[2][4];
    #pragma unroll
    for (int mt = 0; mt < 2; ++mt)
        #pragma unroll
        for (int nn = 0; nn < 4; ++nn)
            acc[mt][nn] = (f32x4){0.f, 0.f, 0.f, 0.f};

    #pragma unroll
    for (int kt = 0; kt < 8; ++kt) {
        #pragma unroll
        for (int nn = 0; nn < 4; ++nn) {
            const int ntg = wv * 4 + nn;
            const bf16x8 bfr = *(const bf16x8*)&Bp[(((ntg * 8 + kt) * 64 + lane) << 3)];
            acc[0][nn] = __builtin_amdgcn_mfma_f32_16x16x32_bf16(afr[0][kt], bfr, acc[0][nn], 0, 0, 0);
            acc[1][nn] = __builtin_amdgcn_mfma_f32_16x16x32_bf16(afr[1][kt], bfr, acc[1][nn], 0, 0, 0);
        }
    }

    const int cl = lane & 15, rq = lane >> 4;
    #pragma unroll
    for (int nn = 0; nn < 4; ++nn) {
        const int col = wv * 64 + nn * 16 + cl;
        const float bb_ = bias[col];
        #pragma unroll
        for (int mt = 0; mt < 2; ++mt) {
            const int row0 = p0 + mt * 16 + rq * 4;
            #pragma unroll
            for (int r2 = 0; r2 < 4; ++r2) {
                out[((size_t)(bbi * LL + l) * PP + row0 + r2) * CC + col] = acc[mt][nn][r2] + bb_;
            }
        }
    }
}

// ---------------------------------------------------------------------------
extern "C" void kernel_launch(void* const* d_in, const int* in_sizes, int n_in,
                              void* d_out, int out_size, void* d_ws, size_t ws_size,
                              hipStream_t stream) {
    const float* x       = (const float*)d_in[0];
    const int*   mask    = (const int*)d_in[1];
    const float* prior   = (const float*)d_in[2];
    const float* lnw     = (const float*)d_in[3];
    const float* lnb     = (const float*)d_in[4];
    const float* Wq      = (const float*)d_in[5];
    const float* bq      = (const float*)d_in[6];
    const float* Wk      = (const float*)d_in[7];
    const float* bk      = (const float*)d_in[8];
    const float* Wv      = (const float*)d_in[9];
    const float* bv      = (const float*)d_in[10];
    const float* Wa      = (const float*)d_in[11];
    const float* ba      = (const float*)d_in[12];
    const float* rel_att = (const float*)d_in[13];
    const float* rel_msg = (const float*)d_in[14];
    float* out = (float*)d_out;

    ushort* qw0   = (ushort*)d_ws;
    ushort* qw1   = qw0 + NTOK;
    ushort* kko   = qw1 + NTOK;
    ushort* vm0   = kko + NTOK;
    ushort* vm1   = vm0 + NTOK;
    ushort* ao    = vm1 + NTOK;
    ushort* packW = ao + NTOK;                 // 12 * 65536 bf16
    float*  bEff  = (float*)(packW + 12 * 65536);   // 2048 fp32

    hipLaunchKernelGGL(k_combine, dim3(192), dim3(256), 0, stream,
                       Wq, Wv, Wk, Wa, bq, bv, rel_att, rel_msg, packW, bEff);
    hipLaunchKernelGGL(k_ln_proj, dim3(640), dim3(256), 0, stream,
                       x, prior, lnw, lnb, packW, bEff, bk, qw0, qw1, kko, vm0, vm1);
    hipLaunchKernelGGL(k_attn_lite, dim3(1024), dim3(256), 0, stream,
                       qw0, qw1, kko, vm0, vm1, mask, prior, ao);
    hipLaunchKernelGGL(k_out_mfma, dim3(640), dim3(256), 0, stream,
                       ao, prior, packW, ba, out);
}